// Round 7
// baseline (122.763 us; speedup 1.0000x reference)
//
#include <hip/hip_runtime.h>
#include <cmath>

// Static problem config (matches reference)
#define RB 20
#define RA 19
#define NPT (RB*RA)
#define DZ 25
#define DIN 9
#define MULT 128
#define CH 128

// ---------------------------------------------------------------------------
// Real-Gaunt selection rules (exact superset of nonzeros; verified R3-R6:
// same absmax as dense). 162 of 2025 (d1,d2,dz) entries survive.
__host__ __device__ constexpr int L_of(int d) { return d == 0 ? 0 : d < 4 ? 1 : d < 9 ? 2 : d < 16 ? 3 : 4; }
__host__ __device__ constexpr int M_of(int d) { return d - L_of(d) * L_of(d) - L_of(d); }
__host__ __device__ constexpr bool gz_nz(int d1, int d2, int dz) {
    const int l1 = L_of(d1), l2 = L_of(d2), l3 = L_of(dz);
    const int m1 = M_of(d1), m2 = M_of(d2), m3 = M_of(dz);
    const int lo = l1 > l2 ? l1 - l2 : l2 - l1;
    if (l3 < lo || l3 > l1 + l2) return false;
    if ((l1 + l2 + l3) & 1) return false;
    const int a1 = m1 < 0 ? -m1 : m1, a2 = m2 < 0 ? -m2 : m2, a3 = m3 < 0 ? -m3 : m3;
    const int sum = a1 + a2, dif = a1 > a2 ? a1 - a2 : a2 - a1;
    if (a3 != sum && a3 != dif) return false;
    if (((m1 < 0) + (m2 < 0) + (m3 < 0)) & 1) return false;
    return true;
}
template<int DZ0, int DZ1>
__host__ __device__ constexpr bool pair_any_r(int d1, int d2) {
    for (int dz = DZ0; dz < DZ1; ++dz) if (gz_nz(d1, d2, dz)) return true;
    return false;
}

// ---------------------------------------------------------------------------
// Host: transposed dense real-Gaunt table Gt[d1*9+d2][28] in fp64 from the
// reference's own quadrature. Cols 25..27 zero pads. Rule-zero entries
// (~1e-16 quadrature noise) forced to exactly 0.0f.
static void host_build_gaunt(float* out /* 81*28, zero-padded */) {
    const double PI = 3.14159265358979323846;
    double xq[RB], wq[RB];
    for (int i = 0; i < RB; ++i) {
        double x = cos(PI * (i + 0.75) / (RB + 0.5));
        double dp = 0.0;
        for (int it = 0; it < 100; ++it) {
            double p0 = 1.0, p1 = x;
            for (int k = 2; k <= RB; ++k) {
                double p2 = ((2.0*k - 1.0)*x*p1 - (k - 1.0)*p0) / (double)k;
                p0 = p1; p1 = p2;
            }
            dp = RB * (x*p1 - p0) / (x*x - 1.0);
            double dx = p1 / dp;
            x -= dx;
            if (fabs(dx) < 1e-15) break;
        }
        {
            double p0 = 1.0, p1 = x;
            for (int k = 2; k <= RB; ++k) {
                double p2 = ((2.0*k - 1.0)*x*p1 - (k - 1.0)*p0) / (double)k;
                p0 = p1; p1 = p2;
            }
            dp = RB * (x*p1 - p0) / (x*x - 1.0);
        }
        xq[i] = x;
        wq[i] = 2.0 / ((1.0 - x*x)*dp*dp);
    }
    static double Y[DZ][NPT];
    static double qws[NPT];
    for (int b = 0; b < RB; ++b) {
        double ct = xq[b], st = sqrt(fmax(0.0, 1.0 - ct*ct));
        double P[5][5]; double pmm = 1.0;
        for (int m = 0; m <= 4; ++m) {
            if (m > 0) pmm *= -(2.0*m - 1.0) * st;
            P[m][m] = pmm;
            if (m < 4) {
                double pp = pmm, pc = ct*(2.0*m + 1.0)*pmm;
                P[m+1][m] = pc;
                for (int l = m + 2; l <= 4; ++l) {
                    double pn = ((2.0*l - 1.0)*ct*pc - (double)(l + m - 1)*pp) / (double)(l - m);
                    P[l][m] = pn; pp = pc; pc = pn;
                }
            }
        }
        for (int a = 0; a < RA; ++a) {
            int pt = b*RA + a;
            qws[pt] = wq[b] * (2.0*PI/(double)RA);
            double alpha = 2.0*PI*(double)a/(double)RA;
            for (int l = 0; l <= 4; ++l)
                for (int m = -l; m <= l; ++m) {
                    int am = m < 0 ? -m : m;
                    double fr = 1.0;
                    for (int i = l - am + 1; i <= l + am; ++i) fr *= (double)i;
                    double nlm = sqrt((2.0*l + 1.0) / (4.0*PI) / fr);
                    double ang = (m == 0) ? 1.0
                               : (m > 0 ? sqrt(2.0)*cos(am*alpha) : sqrt(2.0)*sin(am*alpha));
                    Y[l*l + l + m][pt] = nlm * P[l][am] * ang;
                }
        }
    }
    for (int pr = 0; pr < 81; ++pr) {
        int d1 = pr / 9, d2 = pr % 9;
        for (int d = 0; d < DZ; ++d) {
            double s = 0.0;
            for (int p = 0; p < NPT; ++p)
                s += Y[d][p] * Y[d1][p] * Y[d2][p] * qws[p];
            out[pr*28 + d] = gz_nz(d1, d2, d) ? (float)s : 0.0f;
        }
    }
}

// ---------------------------------------------------------------------------
// Sparse stage C (proven R4 order), node-pair form, dz range [DZ0,DZ1).
template<int DZ0, int DZ1, int D1, int D2, int DZi>
__device__ __forceinline__ void c_dz(const float* __restrict__ g, float p0, float p1,
                                     float* a0, float* a1) {
    if constexpr (DZi < DZ1) {
        if constexpr (gz_nz(D1, D2, DZi)) {
            const float gv = g[(D1 * 9 + D2) * 28 + DZi];   // b32 broadcast
            a0[DZi - DZ0] = fmaf(p0, gv, a0[DZi - DZ0]);
            a1[DZi - DZ0] = fmaf(p1, gv, a1[DZi - DZ0]);
        }
        c_dz<DZ0, DZ1, D1, D2, DZi + 1>(g, p0, p1, a0, a1);
    }
}
template<int DZ0, int DZ1, int D1, int D2>
__device__ __forceinline__ void c_d2(const float* __restrict__ g,
                                     const float* x0, const float* x1,
                                     const float* y0, const float* y1,
                                     float* a0, float* a1) {
    if constexpr (D2 < 9) {
        if constexpr (pair_any_r<DZ0, DZ1>(D1, D2))
            c_dz<DZ0, DZ1, D1, D2, DZ0>(g, x0[D1] * y0[D2], x1[D1] * y1[D2], a0, a1);
        c_d2<DZ0, DZ1, D1, D2 + 1>(g, x0, x1, y0, y1, a0, a1);
    }
}
template<int DZ0, int DZ1, int D1>
__device__ __forceinline__ void c_d1(const float* __restrict__ g,
                                     const float* x0, const float* x1,
                                     const float* y0, const float* y1,
                                     float* a0, float* a1) {
    if constexpr (D1 < 9) {
        c_d2<DZ0, DZ1, D1, 0>(g, x0, x1, y0, y1, a0, a1);
        c_d1<DZ0, DZ1, D1 + 1>(g, x0, x1, y0, y1, a0, a1);
    }
}

// ---------------------------------------------------------------------------
// Stage D, 4 nodes: wave owns l-aligned d-range [D0,D0+ND) covering NL wz
// l-blocks from L0 (wz element read ONCE per block); lane owns e-pair ->
// float2 wz loads; each load feeds 4 nodes (2x the R0 arithmetic intensity).
// Depth-2 prefetch: chunk i's loads issued 2 chunks (~1200 cy of fma) ahead.
// Per-(e,d,n) accumulation order (c0 asc, k asc) identical to R0 -> bit-exact.
template<int D0, int ND, int L0, int NL>
__device__ __forceinline__ void d_tile4(const float* sZ, const float* __restrict__ wz,
                                        float* __restrict__ outp, int lane) {
    const float s128 = 0.08838834764831845f;
    const int e2 = lane << 1;
    float acc[ND * 8];                    // [i][n][e01]
    #pragma unroll
    for (int i = 0; i < ND * 8; ++i) acc[i] = 0.f;
    float2 wA[NL * 4], wB[NL * 4];

    #define LOADW_D(W, C0) { \
        _Pragma("unroll") \
        for (int j = 0; j < NL; ++j) { \
            _Pragma("unroll") \
            for (int k = 0; k < 4; ++k) \
                W[j * 4 + k] = *(const float2*)(wz + (L0 + j) * 16384 + ((C0) + k) * 128 + e2); \
        } }
    #define FMA_D(W, C0) { \
        _Pragma("unroll") \
        for (int i = 0; i < ND; ++i) { \
            const int d = D0 + i; \
            const int l = (d == 0) ? 0 : (d < 4) ? 1 : (d < 9) ? 2 : (d < 16) ? 3 : 4; \
            _Pragma("unroll") \
            for (int n = 0; n < 4; ++n) { \
                float4 z4 = *(const float4*)(sZ + (n * 25 + d) * 128 + (C0));  /* bcast */ \
                _Pragma("unroll") \
                for (int k = 0; k < 4; ++k) { \
                    float zc = (k == 0) ? z4.x : (k == 1) ? z4.y : (k == 2) ? z4.z : z4.w; \
                    acc[(i*4+n)*2+0] = fmaf(zc, W[(l - L0) * 4 + k].x, acc[(i*4+n)*2+0]); \
                    acc[(i*4+n)*2+1] = fmaf(zc, W[(l - L0) * 4 + k].y, acc[(i*4+n)*2+1]); \
                } \
            } \
        } }

    LOADW_D(wA, 0);
    LOADW_D(wB, 4);
    for (int c0 = 0; c0 < CH; c0 += 8) {
        FMA_D(wA, c0);
        if (c0 + 8 < CH) LOADW_D(wA, c0 + 8);     // depth-2 ahead
        FMA_D(wB, c0 + 4);
        if (c0 + 12 < CH) LOADW_D(wB, c0 + 12);
    }
    #undef LOADW_D
    #undef FMA_D

    #pragma unroll
    for (int i = 0; i < ND; ++i)
        #pragma unroll
        for (int n = 0; n < 4; ++n) {
            outp[n * 3200 + e2 * 25 + D0 + i]       = acc[(i*4+n)*2+0] * s128;
            outp[n * 3200 + (e2 + 1) * 25 + D0 + i] = acc[(i*4+n)*2+1] * s128;
        }
}

// ---------------------------------------------------------------------------
// R7: FOUR nodes per block, 256 threads, grid = 256 = exactly 1 block/CU.
// Evidence R0-R6: per-SIMD issue work is only ~18-20us; the other ~34us is
// two LOCKSTEP waves/SIMD stalling simultaneously on w-load chains (~850cy
// effective latency vs ~290cy of depth-1 cover). This round trades TLP
// (2 -> 1 wave/SIMD, same total issue work) for: 2x arithmetic intensity
// per load (4 nodes share each w fetch), depth-2 prefetch (~1200cy cover,
// affordable at 1 wave/SIMD: launch_bounds(256,1) frees the VGPR budget),
// and HALF the chip weight traffic. All per-output fma orders preserved ->
// bit-identical results.
__global__ __launch_bounds__(256, 1) void gaunt_fused(
    const float* __restrict__ xg, const float* __restrict__ yg,
    const float* __restrict__ wxg, const float* __restrict__ wyg,
    const float* __restrict__ wzg, float* __restrict__ outg,
    const float* __restrict__ gGt) {

    // LDS pool (floats), 33500 = 134000 B (1 block/CU):
    //  sXY [0,     9216)  x,y transposed [side][n][d*128+m]  (A/B)
    //  sXc [9216, 18432)  xc [side*9+d][n][c]                (B/C)
    //  sZ  [18432,31232)  z [n][dz][c]                       (C/D)
    //  sG  [31232,33500)  Gaunt table                        (A/C)
    __shared__ __align__(16) float pool[33500];
    float* sXY = pool;
    float* sXc = pool + 9216;
    float* sZ  = pool + 18432;
    float* sG  = pool + 31232;

    const int tid  = threadIdx.x;
    const int nb4  = blockIdx.x * 4;               // first node of this block
    const int lane = tid & 63;
    const int wave = __builtin_amdgcn_readfirstlane(tid >> 6);
    const float s128 = 0.08838834764831845f;       // 1/sqrt(128)

    // Stage A: x,y for nodes nb4..nb4+3 -> transposed sXY; Gaunt table -> sG
    {
        const float4* xs = (const float4*)(xg + (size_t)nb4 * 1152);
        const float4* ys = (const float4*)(yg + (size_t)nb4 * 1152);
        for (int i = tid; i < 2304; i += 256) {
            float4 v = (i < 1152) ? xs[i] : ys[i - 1152];
            int r = (i < 1152) ? i : i - 1152;
            int base = (i < 1152) ? 0 : 4608;
            int j0 = r * 4;
            #pragma unroll
            for (int k = 0; k < 4; ++k) {
                int j = j0 + k;                    // j = n*1152 + m*9 + d
                int n = j / 1152;
                int jj = j - n * 1152;
                int m = jj / 9, d = jj - 9 * m;
                float val = (k == 0) ? v.x : (k == 1) ? v.y : (k == 2) ? v.z : v.w;
                sXY[base + n * 1152 + d * 128 + m] = val;
            }
        }
        for (int i = tid; i < 567; i += 256)
            ((float4*)sG)[i] = ((const float4*)gGt)[i];
    }
    __syncthreads();

    // Stage B: linear_in. wave=(side,chalf), lane owns one c; each w fetch
    // feeds FOUR nodes (144 fma per 12 loads). Depth-2 prefetch. Per-(c,d,n)
    // m-order identical to R0 -> bit-exact.
    {
        const int side = wave >> 1, ch = wave & 1;
        const int c = ch * 64 + lane;
        const float* wb = side ? wyg : wxg;
        const float* xb = sXY + side * 4608;       // [n][d*128+m]
        float acc[36];                              // [d][n]
        #pragma unroll
        for (int i = 0; i < 36; ++i) acc[i] = 0.f;
        float wA[12], wB[12];

        #define LOADW_B(W, M0) { \
            _Pragma("unroll") \
            for (int k = 0; k < 4; ++k) { \
                W[k]     = wb[((M0) + k) * 128 + c]; \
                W[4 + k] = wb[16384 + ((M0) + k) * 128 + c]; \
                W[8 + k] = wb[32768 + ((M0) + k) * 128 + c]; \
            } }
        #define FMA_B(W, M0) { \
            _Pragma("unroll") \
            for (int d = 0; d < 9; ++d) { \
                const int lb = (d == 0) ? 0 : (d < 4) ? 4 : 8; \
                _Pragma("unroll") \
                for (int n = 0; n < 4; ++n) { \
                    float4 xv = *(const float4*)(xb + n * 1152 + d * 128 + (M0));  /* bcast */ \
                    acc[d*4+n] = fmaf(xv.x, W[lb+0], acc[d*4+n]); \
                    acc[d*4+n] = fmaf(xv.y, W[lb+1], acc[d*4+n]); \
                    acc[d*4+n] = fmaf(xv.z, W[lb+2], acc[d*4+n]); \
                    acc[d*4+n] = fmaf(xv.w, W[lb+3], acc[d*4+n]); \
                } \
            } }

        LOADW_B(wA, 0);
        LOADW_B(wB, 4);
        for (int m0 = 0; m0 < MULT; m0 += 8) {
            FMA_B(wA, m0);
            if (m0 + 8 < MULT) LOADW_B(wA, m0 + 8);      // depth-2 ahead
            FMA_B(wB, m0 + 4);
            if (m0 + 12 < MULT) LOADW_B(wB, m0 + 12);
        }
        #undef LOADW_B
        #undef FMA_B

        #pragma unroll
        for (int d = 0; d < 9; ++d)
            #pragma unroll
            for (int n = 0; n < 4; ++n)
                sXc[((side * 9 + d) * 4 + n) * 128 + c] = acc[d*4+n] * s128;
    }
    __syncthreads();

    // Stage C: SPARSE z = G : (xc o yc). thread=(c, dz-half); node pairs
    // processed sequentially (register pressure). 162 rule-allowed terms,
    // R4-proven bit-exact order.
    {
        const int c = tid & 127;
        const int half = __builtin_amdgcn_readfirstlane(tid >> 7);
        #pragma unroll
        for (int np = 0; np < 2; ++np) {           // nodes 2np, 2np+1
            float xr0[9], xr1[9], yr0[9], yr1[9];
            #pragma unroll
            for (int d = 0; d < 9; ++d) {
                xr0[d] = sXc[(d * 4 + np * 2 + 0) * 128 + c];
                xr1[d] = sXc[(d * 4 + np * 2 + 1) * 128 + c];
                yr0[d] = sXc[((9 + d) * 4 + np * 2 + 0) * 128 + c];
                yr1[d] = sXc[((9 + d) * 4 + np * 2 + 1) * 128 + c];
            }
            if (half == 0) {
                float a0[12], a1[12];
                #pragma unroll
                for (int i = 0; i < 12; ++i) { a0[i] = 0.f; a1[i] = 0.f; }
                c_d1<0, 12, 0>(sG, xr0, xr1, yr0, yr1, a0, a1);
                #pragma unroll
                for (int i = 0; i < 12; ++i) {     // dz 0..11
                    sZ[((np * 2 + 0) * 25 + i) * 128 + c] = a0[i];
                    sZ[((np * 2 + 1) * 25 + i) * 128 + c] = a1[i];
                }
            } else {
                float a0[13], a1[13];
                #pragma unroll
                for (int i = 0; i < 13; ++i) { a0[i] = 0.f; a1[i] = 0.f; }
                c_d1<12, 25, 0>(sG, xr0, xr1, yr0, yr1, a0, a1);
                #pragma unroll
                for (int i = 0; i < 13; ++i) {     // dz 12..24
                    sZ[((np * 2 + 0) * 25 + 12 + i) * 128 + c] = a0[i];
                    sZ[((np * 2 + 1) * 25 + 12 + i) * 128 + c] = a1[i];
                }
            }
        }
    }
    __syncthreads();

    // Stage D: linear_out. wave -> l-aligned d-range (wz read once per
    // block), e-pair lanes, 4 nodes per load, direct global stores, no
    // final barrier (waves retire independently).
    float* po = outg + (size_t)nb4 * (CH * DZ);
    if      (wave == 0) d_tile4<0,  4, 0, 2>(sZ, wzg, po, lane);   // l0+l1
    else if (wave == 1) d_tile4<4,  5, 2, 1>(sZ, wzg, po, lane);   // l2
    else if (wave == 2) d_tile4<9,  7, 3, 1>(sZ, wzg, po, lane);   // l3
    else                d_tile4<16, 9, 4, 1>(sZ, wzg, po, lane);   // l4
}

extern "C" void kernel_launch(void* const* d_in, const int* in_sizes, int n_in,
                              void* d_out, int out_size, void* d_ws, size_t ws_size,
                              hipStream_t stream) {
    static float h_gGt[81 * 28];   // zero-init pads
    static bool built = false;
    if (!built) { host_build_gaunt(h_gGt); built = true; }
    hipMemcpyAsync(d_ws, h_gGt, sizeof(h_gGt), hipMemcpyHostToDevice, stream);

    int N = in_sizes[0] / (MULT * DIN);

    hipLaunchKernelGGL(gaunt_fused, dim3(N / 4), dim3(256), 0, stream,
                       (const float*)d_in[0], (const float*)d_in[1],
                       (const float*)d_in[2], (const float*)d_in[3],
                       (const float*)d_in[4], (float*)d_out, (const float*)d_ws);
}

// Round 8
// 109.151 us; speedup vs baseline: 1.1247x; 1.1247x over previous
//
#include <hip/hip_runtime.h>
#include <cmath>

// Static problem config (matches reference)
#define RB 20
#define RA 19
#define NPT (RB*RA)
#define DZ 25
#define DIN 9
#define MULT 128
#define CH 128

// ---------------------------------------------------------------------------
// Real-Gaunt selection rules (exact superset of nonzeros; verified R3-R7:
// same absmax as dense). 162 of 2025 (d1,d2,dz) entries survive.
__host__ __device__ constexpr int L_of(int d) { return d == 0 ? 0 : d < 4 ? 1 : d < 9 ? 2 : d < 16 ? 3 : 4; }
__host__ __device__ constexpr int M_of(int d) { return d - L_of(d) * L_of(d) - L_of(d); }
__host__ __device__ constexpr bool gz_nz(int d1, int d2, int dz) {
    const int l1 = L_of(d1), l2 = L_of(d2), l3 = L_of(dz);
    const int m1 = M_of(d1), m2 = M_of(d2), m3 = M_of(dz);
    const int lo = l1 > l2 ? l1 - l2 : l2 - l1;
    if (l3 < lo || l3 > l1 + l2) return false;
    if ((l1 + l2 + l3) & 1) return false;
    const int a1 = m1 < 0 ? -m1 : m1, a2 = m2 < 0 ? -m2 : m2, a3 = m3 < 0 ? -m3 : m3;
    const int sum = a1 + a2, dif = a1 > a2 ? a1 - a2 : a2 - a1;
    if (a3 != sum && a3 != dif) return false;
    if (((m1 < 0) + (m2 < 0) + (m3 < 0)) & 1) return false;
    return true;
}
template<int DZ0, int DZ1>
__host__ __device__ constexpr bool pair_any_r(int d1, int d2) {
    for (int dz = DZ0; dz < DZ1; ++dz) if (gz_nz(d1, d2, dz)) return true;
    return false;
}

// ---------------------------------------------------------------------------
// Host: transposed dense real-Gaunt table Gt[d1*9+d2][28] in fp64 from the
// reference's own quadrature. Cols 25..27 zero pads. Rule-zero entries
// (~1e-16 quadrature noise) forced to exactly 0.0f.
static void host_build_gaunt(float* out /* 81*28, zero-padded */) {
    const double PI = 3.14159265358979323846;
    double xq[RB], wq[RB];
    for (int i = 0; i < RB; ++i) {
        double x = cos(PI * (i + 0.75) / (RB + 0.5));
        double dp = 0.0;
        for (int it = 0; it < 100; ++it) {
            double p0 = 1.0, p1 = x;
            for (int k = 2; k <= RB; ++k) {
                double p2 = ((2.0*k - 1.0)*x*p1 - (k - 1.0)*p0) / (double)k;
                p0 = p1; p1 = p2;
            }
            dp = RB * (x*p1 - p0) / (x*x - 1.0);
            double dx = p1 / dp;
            x -= dx;
            if (fabs(dx) < 1e-15) break;
        }
        {
            double p0 = 1.0, p1 = x;
            for (int k = 2; k <= RB; ++k) {
                double p2 = ((2.0*k - 1.0)*x*p1 - (k - 1.0)*p0) / (double)k;
                p0 = p1; p1 = p2;
            }
            dp = RB * (x*p1 - p0) / (x*x - 1.0);
        }
        xq[i] = x;
        wq[i] = 2.0 / ((1.0 - x*x)*dp*dp);
    }
    static double Y[DZ][NPT];
    static double qws[NPT];
    for (int b = 0; b < RB; ++b) {
        double ct = xq[b], st = sqrt(fmax(0.0, 1.0 - ct*ct));
        double P[5][5]; double pmm = 1.0;
        for (int m = 0; m <= 4; ++m) {
            if (m > 0) pmm *= -(2.0*m - 1.0) * st;
            P[m][m] = pmm;
            if (m < 4) {
                double pp = pmm, pc = ct*(2.0*m + 1.0)*pmm;
                P[m+1][m] = pc;
                for (int l = m + 2; l <= 4; ++l) {
                    double pn = ((2.0*l - 1.0)*ct*pc - (double)(l + m - 1)*pp) / (double)(l - m);
                    P[l][m] = pn; pp = pc; pc = pn;
                }
            }
        }
        for (int a = 0; a < RA; ++a) {
            int pt = b*RA + a;
            qws[pt] = wq[b] * (2.0*PI/(double)RA);
            double alpha = 2.0*PI*(double)a/(double)RA;
            for (int l = 0; l <= 4; ++l)
                for (int m = -l; m <= l; ++m) {
                    int am = m < 0 ? -m : m;
                    double fr = 1.0;
                    for (int i = l - am + 1; i <= l + am; ++i) fr *= (double)i;
                    double nlm = sqrt((2.0*l + 1.0) / (4.0*PI) / fr);
                    double ang = (m == 0) ? 1.0
                               : (m > 0 ? sqrt(2.0)*cos(am*alpha) : sqrt(2.0)*sin(am*alpha));
                    Y[l*l + l + m][pt] = nlm * P[l][am] * ang;
                }
        }
    }
    for (int pr = 0; pr < 81; ++pr) {
        int d1 = pr / 9, d2 = pr % 9;
        for (int d = 0; d < DZ; ++d) {
            double s = 0.0;
            for (int p = 0; p < NPT; ++p)
                s += Y[d][p] * Y[d1][p] * Y[d2][p] * qws[p];
            out[pr*28 + d] = gz_nz(d1, d2, d) ? (float)s : 0.0f;
        }
    }
}

// ---------------------------------------------------------------------------
// Sparse stage C (R4-proven bit-exact), dz range [DZ0,DZ1), node pair.
template<int DZ0, int DZ1, int D1, int D2, int DZi>
__device__ __forceinline__ void c_dz(const float* __restrict__ g, float p0, float p1,
                                     float* a0, float* a1) {
    if constexpr (DZi < DZ1) {
        if constexpr (gz_nz(D1, D2, DZi)) {
            const float gv = g[(D1 * 9 + D2) * 28 + DZi];   // b32 broadcast
            a0[DZi - DZ0] = fmaf(p0, gv, a0[DZi - DZ0]);
            a1[DZi - DZ0] = fmaf(p1, gv, a1[DZi - DZ0]);
        }
        c_dz<DZ0, DZ1, D1, D2, DZi + 1>(g, p0, p1, a0, a1);
    }
}
template<int DZ0, int DZ1, int D1, int D2>
__device__ __forceinline__ void c_d2(const float* __restrict__ g,
                                     const float* x0, const float* x1,
                                     const float* y0, const float* y1,
                                     float* a0, float* a1) {
    if constexpr (D2 < 9) {
        if constexpr (pair_any_r<DZ0, DZ1>(D1, D2))
            c_dz<DZ0, DZ1, D1, D2, DZ0>(g, x0[D1] * y0[D2], x1[D1] * y1[D2], a0, a1);
        c_d2<DZ0, DZ1, D1, D2 + 1>(g, x0, x1, y0, y1, a0, a1);
    }
}
template<int DZ0, int DZ1, int D1>
__device__ __forceinline__ void c_d1(const float* __restrict__ g,
                                     const float* x0, const float* x1,
                                     const float* y0, const float* y1,
                                     float* a0, float* a1) {
    if constexpr (D1 < 9) {
        c_d2<DZ0, DZ1, D1, 0>(g, x0, x1, y0, y1, a0, a1);
        c_d1<DZ0, DZ1, D1 + 1>(g, x0, x1, y0, y1, a0, a1);
    }
}

// ---------------------------------------------------------------------------
// Stage D helper (R4 verbatim -- best-measured variant): wave owns l-aligned
// d-range [D0,D0+ND) (wz read once per block); lane owns e=lane and e+64;
// both nodes; direct global stores. Per-(e,d) order (c0 asc, k asc).
template<int D0, int ND>
__device__ __forceinline__ void d_tile(const float* sZ, const float* __restrict__ wz,
                                       float* __restrict__ po, int lane) {
    const float s128 = 0.08838834764831845f;
    float acc[ND * 4];
    #pragma unroll
    for (int i = 0; i < ND * 4; ++i) acc[i] = 0.f;
    for (int c0 = 0; c0 < CH; c0 += 4) {
        #pragma unroll
        for (int i = 0; i < ND; ++i) {
            const int d = D0 + i;
            const int l = (d == 0) ? 0 : (d < 4) ? 1 : (d < 9) ? 2 : (d < 16) ? 3 : 4;
            float4 z0 = *(const float4*)(sZ + d * 128 + c0);          // node0 broadcast
            float4 z1 = *(const float4*)(sZ + (25 + d) * 128 + c0);   // node1 broadcast
            #pragma unroll
            for (int k = 0; k < 4; ++k) {
                float wa = wz[l * 16384 + (c0 + k) * 128 + lane];       // CSE across same-l i
                float wb = wz[l * 16384 + (c0 + k) * 128 + lane + 64];
                float zc0 = (k == 0) ? z0.x : (k == 1) ? z0.y : (k == 2) ? z0.z : z0.w;
                float zc1 = (k == 0) ? z1.x : (k == 1) ? z1.y : (k == 2) ? z1.z : z1.w;
                acc[i*4+0] = fmaf(zc0, wa, acc[i*4+0]);
                acc[i*4+1] = fmaf(zc0, wb, acc[i*4+1]);
                acc[i*4+2] = fmaf(zc1, wa, acc[i*4+2]);
                acc[i*4+3] = fmaf(zc1, wb, acc[i*4+3]);
            }
        }
    }
    #pragma unroll
    for (int i = 0; i < ND; ++i) {
        po[lane * 25 + D0 + i]               = acc[i*4+0] * s128;
        po[(lane + 64) * 25 + D0 + i]        = acc[i*4+1] * s128;
        po[3200 + lane * 25 + D0 + i]        = acc[i*4+2] * s128;
        po[3200 + (lane + 64) * 25 + D0 + i] = acc[i*4+3] * s128;
    }
}

// ---------------------------------------------------------------------------
// R8 = R4 minus stage A. Stage B's x index has NO lane dependence (lanes
// differ only in c, which only indexes w) -> x is read DIRECTLY from global
// in native [n][m][d] layout as wave-uniform loads: each (node, m-chunk) is
// 36 CONSECUTIVE floats, which the compiler merges into s_load_dwordx16
// clusters on the scalar/lgkm path (parallel to VALU and vector VMEM).
// Deletes: the transpose (576 float4 loads + ~4600 LDS writes per block),
// one barrier (3 -> 2), and all 576 ds_read_b128 x-broadcasts in B.
// Values and per-output fma orders identical to R4 -> bit-exact.
__global__ __launch_bounds__(256) void gaunt_fused(
    const float* __restrict__ xg, const float* __restrict__ yg,
    const float* __restrict__ wxg, const float* __restrict__ wyg,
    const float* __restrict__ wzg, float* __restrict__ outg,
    const float* __restrict__ gGt) {

    // LDS pool (floats), 13276 = 53104 B:
    //  sXc [0,     4608)  xc [side*9+d][n][c]   (B writes, C reads)
    //  sZ  [4608, 11008)  z [n][dz][c]          (C writes, D reads)
    //  sG  [11008,13276)  Gaunt table           (prologue, C reads)
    __shared__ __align__(16) float pool[13276];
    float* sXc = pool;
    float* sZ  = pool + 4608;
    float* sG  = pool + 11008;

    const int tid  = threadIdx.x;
    const int b    = blockIdx.x;
    const int lane = tid & 63;
    const int wave = __builtin_amdgcn_readfirstlane(tid >> 6);
    const float s128 = 0.08838834764831845f;   // 1/sqrt(128)

    // Prologue: Gaunt table -> sG (no barrier needed; covered by B's barrier)
    for (int i = tid; i < 567; i += 256)
        ((float4*)sG)[i] = ((const float4*)gGt)[i];

    // Stage B: linear_in. wave=(side,chalf), lane owns one c; both nodes
    // share each w fetch (w pattern identical to R0/R4). x read straight
    // from global: 36 consecutive floats per (node, chunk), wave-uniform.
    {
        const int side = wave >> 1, ch = wave & 1;
        const int c = ch * 64 + lane;
        const float* wb = side ? wyg : wxg;
        const float* xb0 = (side ? yg : xg) + (size_t)(2 * b + 0) * 1152;
        const float* xb1 = (side ? yg : xg) + (size_t)(2 * b + 1) * 1152;
        float acc[18];                          // [d][n]
        #pragma unroll
        for (int i = 0; i < 18; ++i) acc[i] = 0.f;
        for (int m0 = 0; m0 < MULT; m0 += 4) {
            float w0[4], w1[4], w2[4];
            #pragma unroll
            for (int k = 0; k < 4; ++k) {
                w0[k] = wb[(m0 + k) * 128 + c];
                w1[k] = wb[16384 + (m0 + k) * 128 + c];
                w2[k] = wb[32768 + (m0 + k) * 128 + c];
            }
            // x for this (chunk): 36 consecutive floats per node, uniform
            // address -> scalar-load clusters. Static indexing -> registers.
            float xa0[36], xa1[36];
            #pragma unroll
            for (int j = 0; j < 36; ++j) {
                xa0[j] = xb0[m0 * 9 + j];       // = x[n0][m0 + j/9][j%9]
                xa1[j] = xb1[m0 * 9 + j];
            }
            #pragma unroll
            for (int d = 0; d < 9; ++d) {
                const float* wl = (d == 0) ? w0 : (d < 4) ? w1 : w2;
                // node0 k asc, then node1 k asc -- same values/order as R4
                acc[d*2+0] = fmaf(xa0[0*9+d], wl[0], acc[d*2+0]);
                acc[d*2+0] = fmaf(xa0[1*9+d], wl[1], acc[d*2+0]);
                acc[d*2+0] = fmaf(xa0[2*9+d], wl[2], acc[d*2+0]);
                acc[d*2+0] = fmaf(xa0[3*9+d], wl[3], acc[d*2+0]);
                acc[d*2+1] = fmaf(xa1[0*9+d], wl[0], acc[d*2+1]);
                acc[d*2+1] = fmaf(xa1[1*9+d], wl[1], acc[d*2+1]);
                acc[d*2+1] = fmaf(xa1[2*9+d], wl[2], acc[d*2+1]);
                acc[d*2+1] = fmaf(xa1[3*9+d], wl[3], acc[d*2+1]);
            }
        }
        #pragma unroll
        for (int d = 0; d < 9; ++d) {
            sXc[((side * 9 + d) * 2 + 0) * 128 + c] = acc[d*2+0] * s128;
            sXc[((side * 9 + d) * 2 + 1) * 128 + c] = acc[d*2+1] * s128;
        }
    }
    __syncthreads();

    // Stage C: SPARSE z = G : (xc o yc). thread=(c, dz-half), both nodes;
    // 162 rule-allowed terms (R4-proven bit-exact order).
    {
        const int c = tid & 127;
        const int half = __builtin_amdgcn_readfirstlane(tid >> 7);
        float xr0[9], xr1[9], yr0[9], yr1[9];
        #pragma unroll
        for (int d = 0; d < 9; ++d) {
            xr0[d] = sXc[(d * 2 + 0) * 128 + c];
            xr1[d] = sXc[(d * 2 + 1) * 128 + c];
            yr0[d] = sXc[((9 + d) * 2 + 0) * 128 + c];
            yr1[d] = sXc[((9 + d) * 2 + 1) * 128 + c];
        }
        if (half == 0) {
            float a0[12], a1[12];
            #pragma unroll
            for (int i = 0; i < 12; ++i) { a0[i] = 0.f; a1[i] = 0.f; }
            c_d1<0, 12, 0>(sG, xr0, xr1, yr0, yr1, a0, a1);
            #pragma unroll
            for (int i = 0; i < 12; ++i) {      // dz 0..11
                sZ[i * 128 + c]        = a0[i];
                sZ[(25 + i) * 128 + c] = a1[i];
            }
        } else {
            float a0[13], a1[13];
            #pragma unroll
            for (int i = 0; i < 13; ++i) { a0[i] = 0.f; a1[i] = 0.f; }
            c_d1<12, 25, 0>(sG, xr0, xr1, yr0, yr1, a0, a1);
            #pragma unroll
            for (int i = 0; i < 13; ++i) {      // dz 12..24
                sZ[(12 + i) * 128 + c] = a0[i];
                sZ[(37 + i) * 128 + c] = a1[i];
            }
        }
    }
    __syncthreads();

    // Stage D: linear_out, wave -> l-aligned d-range, direct global stores,
    // no final barrier (waves retire independently).
    float* po = outg + 2 * b * (CH * DZ);
    if      (wave == 0) d_tile<0, 4>(sZ, wzg, po, lane);   // l0+l1
    else if (wave == 1) d_tile<4, 5>(sZ, wzg, po, lane);   // l2
    else if (wave == 2) d_tile<9, 7>(sZ, wzg, po, lane);   // l3
    else                d_tile<16, 9>(sZ, wzg, po, lane);  // l4
}

extern "C" void kernel_launch(void* const* d_in, const int* in_sizes, int n_in,
                              void* d_out, int out_size, void* d_ws, size_t ws_size,
                              hipStream_t stream) {
    static float h_gGt[81 * 28];   // zero-init pads
    static bool built = false;
    if (!built) { host_build_gaunt(h_gGt); built = true; }
    hipMemcpyAsync(d_ws, h_gGt, sizeof(h_gGt), hipMemcpyHostToDevice, stream);

    int N = in_sizes[0] / (MULT * DIN);

    hipLaunchKernelGGL(gaunt_fused, dim3(N / 2), dim3(256), 0, stream,
                       (const float*)d_in[0], (const float*)d_in[1],
                       (const float*)d_in[2], (const float*)d_in[3],
                       (const float*)d_in[4], (float*)d_out, (const float*)d_ws);
}